// Round 14
// baseline (104.024 us; speedup 1.0000x reference)
//
#include <hip/hip_runtime.h>
#include <cstddef>

#define NUM_VARS_ 784
#define NUM_PARAM_ 64
#define NET_DIM_ 64
#define FF_DIM_ 64
#define QTOT_ 2048
#define QCHUNK_ 2048  // grid (1, 784): each group's weights fetched by ONE block

typedef short v8s __attribute__((ext_vector_type(8)));
typedef short v4s_ __attribute__((ext_vector_type(4)));
typedef float v4f __attribute__((ext_vector_type(4)));

__device__ __forceinline__ short f2bf(float x) {
  union { float f; unsigned u; } c; c.f = x;
  unsigned r = c.u + 0x7FFFu + ((c.u >> 16) & 1u);
  return (short)(r >> 16);
}

// 1 - 2/(e^2x + 1). No clamp: exp2->inf->rcp->0 gives +1; exp2->0 gives -1.
__device__ __forceinline__ float fast_tanh(float x) {
  float t = __builtin_amdgcn_exp2f(x * 2.8853900817779268f);
  return 1.0f - 2.0f * __builtin_amdgcn_rcpf(t + 1.0f);
}

// ---- Tiny prologue: Fourier features only (256 KB).
__global__ __launch_bounds__(256) void feat_kernel(
    const float* __restrict__ z, const float* __restrict__ coeff,
    short* __restrict__ featbf) {
  int i = blockIdx.x * 256 + threadIdx.x;
  if (i >= QTOT_ * FF_DIM_) return;
  int q = i >> 6, j = i & 63;
  float arg = (6.2831853071795865f * z[q]) * coeff[j & 31];
  float v = (j < 32) ? cosf(arg) : sinf(arg);
  featbf[i] = f2bf(v);
}

// ---- Fused main: block = (full Q range, group g); 4 waves, each wave owns
// 512 q rows (32 m-frags of 16).
// Phase 0: block cooperatively streams its group's 32KB f32 weights
// (coalesced dwordx4, independent loads, bounded live range), bf16 -> LDS
// (reusing sbuf), barrier, lanes read v8s fragments. One block per group ->
// weight HBM traffic at the 25MB minimum, no cross-XCD duplication.
// Loop: GEMM1 = W1 x feat^T -> tanh -> LDS -> GEMM2 = W2 x h (D=[p][q]) ->
// LDS-transpose epilogue -> 4 x 1KB contiguous NONTEMPORAL stores.
__global__ __launch_bounds__(256) void picnet_main(
    const float* __restrict__ W1, const float* __restrict__ W2,
    const short* __restrict__ featbf, float* __restrict__ out) {
  const int g = blockIdx.y;
  const int qc = blockIdx.x;
  const int tid = threadIdx.x;
  const int w = tid >> 6;
  const int lane = tid & 63;
  const int lo = lane & 15;
  const int hi = lane >> 4;

  // per-wave h slice: hl[q_local][n], 16 x 64, stride 72 (pad).
  __shared__ __align__(16) short hl[4][16][72];
  // per-wave f32 output staging tile: 16 x 64, stride 68 (pad 4).
  // ALSO reused (before the main loop) as the bf16 weight staging buffer:
  // needs 8192 shorts = 16 KB <= 17.4 KB.
  __shared__ __align__(16) float sbuf[4][16][68];

  // Phase 0: f32 weights -> bf16 in LDS.
  short* wlds = (short*)&sbuf[0][0][0];
  {
    const float* W1g = W1 + (size_t)g * 4096;
    const float* W2g = W2 + (size_t)g * 4096;
#pragma unroll
    for (int c = 0; c < 8; ++c) {
      int idx = c * 1024 + tid * 4;  // f32 index in [0, 8192)
      const float* src = (idx < 4096) ? (W1g + idx) : (W2g + (idx - 4096));
      float4 v = *(const float4*)src;
      v4s_ s;
      s[0] = f2bf(v.x); s[1] = f2bf(v.y); s[2] = f2bf(v.z); s[3] = f2bf(v.w);
      *(v4s_*)(wlds + idx) = s;
    }
  }
  __syncthreads();

  // Weight fragments in VGPRs for the whole block.
  // b1[f]: GEMM1 A-frag (row n = 16f+lo, k = k0*32 + hi*8 + j)
  // b2[f]: GEMM2 A-frag (row p = 16f+lo, k(=n) = k0*32 + hi*8 + j)
  v8s b1[4][2], b2[4][2];
#pragma unroll
  for (int f = 0; f < 4; ++f)
#pragma unroll
    for (int k0 = 0; k0 < 2; ++k0) {
      b1[f][k0] = *(const v8s*)(wlds + (16 * f + lo) * 64 + k0 * 32 + hi * 8);
      b2[f][k0] = *(const v8s*)(wlds + 4096 + (16 * f + lo) * 64 + k0 * 32 + hi * 8);
    }
  __syncthreads();  // wlds -> sbuf role switch

  const int qbase = qc * QCHUNK_ + w * (QCHUNK_ / 4);
  const short* fp0 = featbf + (size_t)(qbase + lo) * 64 + hi * 8;

  // software-pipelined feat B-frags (B[k][q]: col q = lo, k = hi*8+j)
  v8s a0 = *(const v8s*)fp0;
  v8s a1 = *(const v8s*)(fp0 + 32);

  float (*B)[68] = sbuf[w];

#pragma unroll 1
  for (int mf = 0; mf < QCHUNK_ / 4 / 16; ++mf) {
    const int q0 = qbase + mf * 16;

    v8s na0, na1;
    if (mf < QCHUNK_ / 4 / 16 - 1) {
      const short* fp = fp0 + (size_t)(mf + 1) * 16 * 64;
      na0 = *(const v8s*)fp;
      na1 = *(const v8s*)(fp + 32);
    }

    // GEMM1: D[n][q] = sum_k W1[n][k] feat[q][k]
    v4f acc[4] = {{0,0,0,0},{0,0,0,0},{0,0,0,0},{0,0,0,0}};
#pragma unroll
    for (int f = 0; f < 4; ++f) {
      acc[f] = __builtin_amdgcn_mfma_f32_16x16x32_bf16(b1[f][0], a0, acc[f], 0, 0, 0);
      acc[f] = __builtin_amdgcn_mfma_f32_16x16x32_bf16(b1[f][1], a1, acc[f], 0, 0, 0);
    }

    // D: col = lo = q_local, row = hi*4+r = n within 16-block f.
    // 4 consecutive n per lane -> packed ds_write_b64 into hl[q][n].
#pragma unroll
    for (int f = 0; f < 4; ++f) {
      v4s_ s;
      s[0] = f2bf(fast_tanh(acc[f][0]));
      s[1] = f2bf(fast_tanh(acc[f][1]));
      s[2] = f2bf(fast_tanh(acc[f][2]));
      s[3] = f2bf(fast_tanh(acc[f][3]));
      *(v4s_*)(&hl[w][lo][16 * f + hi * 4]) = s;
    }

    // GEMM2 B-frag from LDS: B[k=n][q]: col q = lo, k = k0*32 + hi*8 + j
    v8s h0 = *(const v8s*)(&hl[w][lo][hi * 8]);
    v8s h1 = *(const v8s*)(&hl[w][lo][32 + hi * 8]);

    // GEMM2: D[p][q] = sum_n W2[p][n] h[n][q]
    v4f acc2[4] = {{0,0,0,0},{0,0,0,0},{0,0,0,0},{0,0,0,0}};
#pragma unroll
    for (int f = 0; f < 4; ++f) {
      acc2[f] = __builtin_amdgcn_mfma_f32_16x16x32_bf16(b2[f][0], h0, acc2[f], 0, 0, 0);
      acc2[f] = __builtin_amdgcn_mfma_f32_16x16x32_bf16(b2[f][1], h1, acc2[f], 0, 0, 0);
    }

    // Epilogue: stage [q_local=16][p=64] f32 tile in LDS, read back
    // lane-contiguous, store 4 x 1KB contiguous chunks NONTEMPORAL.
    // Write: lane (lo,hi) holds q=lo, p = hi*4+16f+r.
#pragma unroll
    for (int f = 0; f < 4; ++f) {
      *(v4f*)(&B[lo][16 * f + hi * 4]) = acc2[f];
    }
    // Read: chunk jj covers rows jj*4..jj*4+3; lane covers 16B at linear
    // offset jj*1KB + lane*16B: q = jj*4 + hi, p = lo*4.
    float* og = out + ((size_t)g * QTOT_ + q0) * 64;
#pragma unroll
    for (int jj = 0; jj < 4; ++jj) {
      v4f v = *(const v4f*)(&B[jj * 4 + hi][lo * 4]);
      __builtin_nontemporal_store(v, (v4f*)(og + jj * 256 + lane * 4));
    }

    a0 = na0; a1 = na1;
  }
}

extern "C" void kernel_launch(void* const* d_in, const int* in_sizes, int n_in,
                              void* d_out, int out_size, void* d_ws, size_t ws_size,
                              hipStream_t stream) {
  const float* z     = (const float*)d_in[0];
  const float* coeff = (const float*)d_in[1];
  const float* W1    = (const float*)d_in[2];
  const float* W2    = (const float*)d_in[3];
  float* out = (float*)d_out;

  short* featbf = (short*)d_ws;  // 2048*64*2 = 256 KB

  feat_kernel<<<dim3((QTOT_ * FF_DIM_ + 255) / 256), dim3(256), 0, stream>>>(
      z, coeff, featbf);
  picnet_main<<<dim3(QTOT_ / QCHUNK_, NUM_VARS_), dim3(256), 0, stream>>>(
      W1, W2, featbf, out);
}

// Round 15
// 88.083 us; speedup vs baseline: 1.1810x; 1.1810x over previous
//
#include <hip/hip_runtime.h>
#include <cstddef>

#define NUM_VARS_ 784
#define NUM_PARAM_ 64
#define NET_DIM_ 64
#define FF_DIM_ 64
#define QTOT_ 2048
#define QCHUNK_ 512
#define NWG_ (NUM_VARS_ * (QTOT_ / QCHUNK_))  // 3136, divisible by 8
#define CPX_ (NWG_ / 8)                       // 392 blocks per XCD chunk

typedef short v8s __attribute__((ext_vector_type(8)));
typedef short v4s_ __attribute__((ext_vector_type(4)));
typedef float v4f __attribute__((ext_vector_type(4)));

__device__ __forceinline__ short f2bf(float x) {
  union { float f; unsigned u; } c; c.f = x;
  unsigned r = c.u + 0x7FFFu + ((c.u >> 16) & 1u);
  return (short)(r >> 16);
}

// 1 - 2/(e^2x + 1). No clamp: exp2->inf->rcp->0 gives +1; exp2->0 gives -1.
__device__ __forceinline__ float fast_tanh(float x) {
  float t = __builtin_amdgcn_exp2f(x * 2.8853900817779268f);
  return 1.0f - 2.0f * __builtin_amdgcn_rcpf(t + 1.0f);
}

// ---- Tiny prologue: Fourier features only (256 KB).
__global__ __launch_bounds__(256) void feat_kernel(
    const float* __restrict__ z, const float* __restrict__ coeff,
    short* __restrict__ featbf) {
  int i = blockIdx.x * 256 + threadIdx.x;
  if (i >= QTOT_ * FF_DIM_) return;
  int q = i >> 6, j = i & 63;
  float arg = (6.2831853071795865f * z[q]) * coeff[j & 31];
  float v = (j < 32) ? cosf(arg) : sinf(arg);
  featbf[i] = f2bf(v);
}

// ---- Fused main (R13 structure, 90.4us) + XCD-aware block swizzle.
// Block = (q-chunk of 512, group g); 4 waves, each wave owns 128 q rows
// (8 m-frags of 16).
// Swizzle: dispatch round-robins linear block ids across 8 XCDs; remapping
// lid' = (lid%8)*CPX + lid/8 puts the 4 same-g blocks on ONE XCD (4 | CPX),
// so each group's 32KB f32 weights are fetched once per XCD into its L2.
// Phase 0: block cooperatively streams its group's 32KB f32 weights
// (coalesced dwordx4, independent loads), bf16 -> LDS (reusing sbuf),
// barrier, lanes read v8s fragments.
// Loop: GEMM1 = W1 x feat^T -> tanh -> LDS -> GEMM2 = W2 x h (D=[p][q]) ->
// LDS-transpose epilogue -> 4 x 1KB contiguous NONTEMPORAL stores.
__global__ __launch_bounds__(256) void picnet_main(
    const float* __restrict__ W1, const float* __restrict__ W2,
    const short* __restrict__ featbf, float* __restrict__ out) {
  // XCD swizzle (bijective: NWG_ % 8 == 0)
  const int lid = blockIdx.x + (QTOT_ / QCHUNK_) * blockIdx.y;
  const int swz = (lid & 7) * CPX_ + (lid >> 3);
  const int g = swz >> 2;         // swz / (QTOT_/QCHUNK_)
  const int qc = swz & 3;         // swz % (QTOT_/QCHUNK_)
  const int tid = threadIdx.x;
  const int w = tid >> 6;
  const int lane = tid & 63;
  const int lo = lane & 15;
  const int hi = lane >> 4;

  // per-wave h slice: hl[q_local][n], 16 x 64, stride 72 (pad).
  __shared__ __align__(16) short hl[4][16][72];
  // per-wave f32 output staging tile: 16 x 64, stride 68 (pad 4).
  // ALSO reused (before the main loop) as the bf16 weight staging buffer:
  // needs 8192 shorts = 16 KB <= 17.4 KB.
  __shared__ __align__(16) float sbuf[4][16][68];

  // Phase 0: f32 weights -> bf16 in LDS.
  short* wlds = (short*)&sbuf[0][0][0];
  {
    const float* W1g = W1 + (size_t)g * 4096;
    const float* W2g = W2 + (size_t)g * 4096;
#pragma unroll
    for (int c = 0; c < 8; ++c) {
      int idx = c * 1024 + tid * 4;  // f32 index in [0, 8192)
      const float* src = (idx < 4096) ? (W1g + idx) : (W2g + (idx - 4096));
      float4 v = *(const float4*)src;
      v4s_ s;
      s[0] = f2bf(v.x); s[1] = f2bf(v.y); s[2] = f2bf(v.z); s[3] = f2bf(v.w);
      *(v4s_*)(wlds + idx) = s;
    }
  }
  __syncthreads();

  // Weight fragments in VGPRs for the whole block.
  // b1[f]: GEMM1 A-frag (row n = 16f+lo, k = k0*32 + hi*8 + j)
  // b2[f]: GEMM2 A-frag (row p = 16f+lo, k(=n) = k0*32 + hi*8 + j)
  v8s b1[4][2], b2[4][2];
#pragma unroll
  for (int f = 0; f < 4; ++f)
#pragma unroll
    for (int k0 = 0; k0 < 2; ++k0) {
      b1[f][k0] = *(const v8s*)(wlds + (16 * f + lo) * 64 + k0 * 32 + hi * 8);
      b2[f][k0] = *(const v8s*)(wlds + 4096 + (16 * f + lo) * 64 + k0 * 32 + hi * 8);
    }
  __syncthreads();  // wlds -> sbuf role switch

  const int qbase = qc * QCHUNK_ + w * (QCHUNK_ / 4);
  const short* fp0 = featbf + (size_t)(qbase + lo) * 64 + hi * 8;

  // software-pipelined feat B-frags (B[k][q]: col q = lo, k = hi*8+j)
  v8s a0 = *(const v8s*)fp0;
  v8s a1 = *(const v8s*)(fp0 + 32);

  float (*B)[68] = sbuf[w];

#pragma unroll 1
  for (int mf = 0; mf < QCHUNK_ / 4 / 16; ++mf) {
    const int q0 = qbase + mf * 16;

    v8s na0, na1;
    if (mf < QCHUNK_ / 4 / 16 - 1) {
      const short* fp = fp0 + (size_t)(mf + 1) * 16 * 64;
      na0 = *(const v8s*)fp;
      na1 = *(const v8s*)(fp + 32);
    }

    // GEMM1: D[n][q] = sum_k W1[n][k] feat[q][k]
    v4f acc[4] = {{0,0,0,0},{0,0,0,0},{0,0,0,0},{0,0,0,0}};
#pragma unroll
    for (int f = 0; f < 4; ++f) {
      acc[f] = __builtin_amdgcn_mfma_f32_16x16x32_bf16(b1[f][0], a0, acc[f], 0, 0, 0);
      acc[f] = __builtin_amdgcn_mfma_f32_16x16x32_bf16(b1[f][1], a1, acc[f], 0, 0, 0);
    }

    // D: col = lo = q_local, row = hi*4+r = n within 16-block f.
    // 4 consecutive n per lane -> packed ds_write_b64 into hl[q][n].
#pragma unroll
    for (int f = 0; f < 4; ++f) {
      v4s_ s;
      s[0] = f2bf(fast_tanh(acc[f][0]));
      s[1] = f2bf(fast_tanh(acc[f][1]));
      s[2] = f2bf(fast_tanh(acc[f][2]));
      s[3] = f2bf(fast_tanh(acc[f][3]));
      *(v4s_*)(&hl[w][lo][16 * f + hi * 4]) = s;
    }

    // GEMM2 B-frag from LDS: B[k=n][q]: col q = lo, k = k0*32 + hi*8 + j
    v8s h0 = *(const v8s*)(&hl[w][lo][hi * 8]);
    v8s h1 = *(const v8s*)(&hl[w][lo][32 + hi * 8]);

    // GEMM2: D[p][q] = sum_n W2[p][n] h[n][q]
    v4f acc2[4] = {{0,0,0,0},{0,0,0,0},{0,0,0,0},{0,0,0,0}};
#pragma unroll
    for (int f = 0; f < 4; ++f) {
      acc2[f] = __builtin_amdgcn_mfma_f32_16x16x32_bf16(b2[f][0], h0, acc2[f], 0, 0, 0);
      acc2[f] = __builtin_amdgcn_mfma_f32_16x16x32_bf16(b2[f][1], h1, acc2[f], 0, 0, 0);
    }

    // Epilogue: stage [q_local=16][p=64] f32 tile in LDS, read back
    // lane-contiguous, store 4 x 1KB contiguous chunks NONTEMPORAL.
    // Write: lane (lo,hi) holds q=lo, p = hi*4+16f+r.
#pragma unroll
    for (int f = 0; f < 4; ++f) {
      *(v4f*)(&B[lo][16 * f + hi * 4]) = acc2[f];
    }
    // Read: chunk jj covers rows jj*4..jj*4+3; lane covers 16B at linear
    // offset jj*1KB + lane*16B: q = jj*4 + hi, p = lo*4.
    float* og = out + ((size_t)g * QTOT_ + q0) * 64;
#pragma unroll
    for (int jj = 0; jj < 4; ++jj) {
      v4f v = *(const v4f*)(&B[jj * 4 + hi][lo * 4]);
      __builtin_nontemporal_store(v, (v4f*)(og + jj * 256 + lane * 4));
    }

    a0 = na0; a1 = na1;
  }
}

extern "C" void kernel_launch(void* const* d_in, const int* in_sizes, int n_in,
                              void* d_out, int out_size, void* d_ws, size_t ws_size,
                              hipStream_t stream) {
  const float* z     = (const float*)d_in[0];
  const float* coeff = (const float*)d_in[1];
  const float* W1    = (const float*)d_in[2];
  const float* W2    = (const float*)d_in[3];
  float* out = (float*)d_out;

  short* featbf = (short*)d_ws;  // 2048*64*2 = 256 KB

  feat_kernel<<<dim3((QTOT_ * FF_DIM_ + 255) / 256), dim3(256), 0, stream>>>(
      z, coeff, featbf);
  picnet_main<<<dim3(QTOT_ / QCHUNK_, NUM_VARS_), dim3(256), 0, stream>>>(
      W1, W2, featbf, out);
}

// Round 16
// 83.300 us; speedup vs baseline: 1.2488x; 1.0574x over previous
//
#include <hip/hip_runtime.h>
#include <cstddef>

#define NUM_VARS_ 784
#define NUM_PARAM_ 64
#define NET_DIM_ 64
#define FF_DIM_ 64
#define QTOT_ 2048
#define QCHUNK_ 256
#define NCH_ (QTOT_ / QCHUNK_)                // 8 q-chunks per group
#define NWG_ (NUM_VARS_ * NCH_)               // 6272, divisible by 8
#define CPX_ (NWG_ / 8)                       // 784 blocks per XCD chunk (8|784)

typedef short v8s __attribute__((ext_vector_type(8)));
typedef short v4s_ __attribute__((ext_vector_type(4)));
typedef float v4f __attribute__((ext_vector_type(4)));

__device__ __forceinline__ short f2bf(float x) {
  union { float f; unsigned u; } c; c.f = x;
  unsigned r = c.u + 0x7FFFu + ((c.u >> 16) & 1u);
  return (short)(r >> 16);
}

// 1 - 2/(e^2x + 1). No clamp: exp2->inf->rcp->0 gives +1; exp2->0 gives -1.
__device__ __forceinline__ float fast_tanh(float x) {
  float t = __builtin_amdgcn_exp2f(x * 2.8853900817779268f);
  return 1.0f - 2.0f * __builtin_amdgcn_rcpf(t + 1.0f);
}

// ---- Tiny prologue: Fourier features only (256 KB).
__global__ __launch_bounds__(256) void feat_kernel(
    const float* __restrict__ z, const float* __restrict__ coeff,
    short* __restrict__ featbf) {
  int i = blockIdx.x * 256 + threadIdx.x;
  if (i >= QTOT_ * FF_DIM_) return;
  int q = i >> 6, j = i & 63;
  float arg = (6.2831853071795865f * z[q]) * coeff[j & 31];
  float v = (j < 32) ? cosf(arg) : sinf(arg);
  featbf[i] = f2bf(v);
}

// ---- Fused main (R14 structure + QCHUNK 256 for tail smoothing:
// 6272 blocks = 24.5 blocks/CU, tail loss ~5us -> ~2us).
// Block = (q-chunk of 256, group g); 4 waves, each wave owns 64 q rows
// (4 m-frags of 16).
// XCD swizzle: lid' = (lid%8)*CPX + lid/8 puts the 8 same-g blocks on ONE
// XCD (8 | CPX), so each group's weights are fetched once per XCD into L2.
// Phase 0: block cooperatively streams its group's 32KB f32 weights
// (coalesced dwordx4, independent loads), bf16 -> LDS (reusing sbuf),
// barrier, lanes read v8s fragments.
// Loop: GEMM1 = W1 x feat^T -> tanh -> LDS -> GEMM2 = W2 x h (D=[p][q]) ->
// LDS-transpose epilogue -> 4 x 1KB contiguous NONTEMPORAL stores.
__global__ __launch_bounds__(256) void picnet_main(
    const float* __restrict__ W1, const float* __restrict__ W2,
    const short* __restrict__ featbf, float* __restrict__ out) {
  // XCD swizzle (bijective: NWG_ % 8 == 0)
  const int lid = blockIdx.x + NCH_ * blockIdx.y;
  const int swz = (lid & 7) * CPX_ + (lid >> 3);
  const int g = swz >> 3;         // swz / NCH_
  const int qc = swz & 7;         // swz % NCH_
  const int tid = threadIdx.x;
  const int w = tid >> 6;
  const int lane = tid & 63;
  const int lo = lane & 15;
  const int hi = lane >> 4;

  // per-wave h slice: hl[q_local][n], 16 x 64, stride 72 (pad).
  __shared__ __align__(16) short hl[4][16][72];
  // per-wave f32 output staging tile: 16 x 64, stride 68 (pad 4).
  // ALSO reused (before the main loop) as the bf16 weight staging buffer:
  // needs 8192 shorts = 16 KB <= 17.4 KB.
  __shared__ __align__(16) float sbuf[4][16][68];

  // Phase 0: f32 weights -> bf16 in LDS.
  short* wlds = (short*)&sbuf[0][0][0];
  {
    const float* W1g = W1 + (size_t)g * 4096;
    const float* W2g = W2 + (size_t)g * 4096;
#pragma unroll
    for (int c = 0; c < 8; ++c) {
      int idx = c * 1024 + tid * 4;  // f32 index in [0, 8192)
      const float* src = (idx < 4096) ? (W1g + idx) : (W2g + (idx - 4096));
      float4 v = *(const float4*)src;
      v4s_ s;
      s[0] = f2bf(v.x); s[1] = f2bf(v.y); s[2] = f2bf(v.z); s[3] = f2bf(v.w);
      *(v4s_*)(wlds + idx) = s;
    }
  }
  __syncthreads();

  // Weight fragments in VGPRs for the whole block.
  // b1[f]: GEMM1 A-frag (row n = 16f+lo, k = k0*32 + hi*8 + j)
  // b2[f]: GEMM2 A-frag (row p = 16f+lo, k(=n) = k0*32 + hi*8 + j)
  v8s b1[4][2], b2[4][2];
#pragma unroll
  for (int f = 0; f < 4; ++f)
#pragma unroll
    for (int k0 = 0; k0 < 2; ++k0) {
      b1[f][k0] = *(const v8s*)(wlds + (16 * f + lo) * 64 + k0 * 32 + hi * 8);
      b2[f][k0] = *(const v8s*)(wlds + 4096 + (16 * f + lo) * 64 + k0 * 32 + hi * 8);
    }
  __syncthreads();  // wlds -> sbuf role switch

  const int qbase = qc * QCHUNK_ + w * (QCHUNK_ / 4);
  const short* fp0 = featbf + (size_t)(qbase + lo) * 64 + hi * 8;

  // software-pipelined feat B-frags (B[k][q]: col q = lo, k = hi*8+j)
  v8s a0 = *(const v8s*)fp0;
  v8s a1 = *(const v8s*)(fp0 + 32);

  float (*B)[68] = sbuf[w];

#pragma unroll 1
  for (int mf = 0; mf < QCHUNK_ / 4 / 16; ++mf) {
    const int q0 = qbase + mf * 16;

    v8s na0, na1;
    if (mf < QCHUNK_ / 4 / 16 - 1) {
      const short* fp = fp0 + (size_t)(mf + 1) * 16 * 64;
      na0 = *(const v8s*)fp;
      na1 = *(const v8s*)(fp + 32);
    }

    // GEMM1: D[n][q] = sum_k W1[n][k] feat[q][k]
    v4f acc[4] = {{0,0,0,0},{0,0,0,0},{0,0,0,0},{0,0,0,0}};
#pragma unroll
    for (int f = 0; f < 4; ++f) {
      acc[f] = __builtin_amdgcn_mfma_f32_16x16x32_bf16(b1[f][0], a0, acc[f], 0, 0, 0);
      acc[f] = __builtin_amdgcn_mfma_f32_16x16x32_bf16(b1[f][1], a1, acc[f], 0, 0, 0);
    }

    // D: col = lo = q_local, row = hi*4+r = n within 16-block f.
    // 4 consecutive n per lane -> packed ds_write_b64 into hl[q][n].
#pragma unroll
    for (int f = 0; f < 4; ++f) {
      v4s_ s;
      s[0] = f2bf(fast_tanh(acc[f][0]));
      s[1] = f2bf(fast_tanh(acc[f][1]));
      s[2] = f2bf(fast_tanh(acc[f][2]));
      s[3] = f2bf(fast_tanh(acc[f][3]));
      *(v4s_*)(&hl[w][lo][16 * f + hi * 4]) = s;
    }

    // GEMM2 B-frag from LDS: B[k=n][q]: col q = lo, k = k0*32 + hi*8 + j
    v8s h0 = *(const v8s*)(&hl[w][lo][hi * 8]);
    v8s h1 = *(const v8s*)(&hl[w][lo][32 + hi * 8]);

    // GEMM2: D[p][q] = sum_n W2[p][n] h[n][q]
    v4f acc2[4] = {{0,0,0,0},{0,0,0,0},{0,0,0,0},{0,0,0,0}};
#pragma unroll
    for (int f = 0; f < 4; ++f) {
      acc2[f] = __builtin_amdgcn_mfma_f32_16x16x32_bf16(b2[f][0], h0, acc2[f], 0, 0, 0);
      acc2[f] = __builtin_amdgcn_mfma_f32_16x16x32_bf16(b2[f][1], h1, acc2[f], 0, 0, 0);
    }

    // Epilogue: stage [q_local=16][p=64] f32 tile in LDS, read back
    // lane-contiguous, store 4 x 1KB contiguous chunks NONTEMPORAL.
    // Write: lane (lo,hi) holds q=lo, p = hi*4+16f+r.
#pragma unroll
    for (int f = 0; f < 4; ++f) {
      *(v4f*)(&B[lo][16 * f + hi * 4]) = acc2[f];
    }
    // Read: chunk jj covers rows jj*4..jj*4+3; lane covers 16B at linear
    // offset jj*1KB + lane*16B: q = jj*4 + hi, p = lo*4.
    float* og = out + ((size_t)g * QTOT_ + q0) * 64;
#pragma unroll
    for (int jj = 0; jj < 4; ++jj) {
      v4f v = *(const v4f*)(&B[jj * 4 + hi][lo * 4]);
      __builtin_nontemporal_store(v, (v4f*)(og + jj * 256 + lane * 4));
    }

    a0 = na0; a1 = na1;
  }
}

extern "C" void kernel_launch(void* const* d_in, const int* in_sizes, int n_in,
                              void* d_out, int out_size, void* d_ws, size_t ws_size,
                              hipStream_t stream) {
  const float* z     = (const float*)d_in[0];
  const float* coeff = (const float*)d_in[1];
  const float* W1    = (const float*)d_in[2];
  const float* W2    = (const float*)d_in[3];
  float* out = (float*)d_out;

  short* featbf = (short*)d_ws;  // 2048*64*2 = 256 KB

  feat_kernel<<<dim3((QTOT_ * FF_DIM_ + 255) / 256), dim3(256), 0, stream>>>(
      z, coeff, featbf);
  picnet_main<<<dim3(NCH_, NUM_VARS_), dim3(256), 0, stream>>>(
      W1, W2, featbf, out);
}